// Round 2
// baseline (338.231 us; speedup 1.0000x reference)
//
#include <hip/hip_runtime.h>

// Problem constants (from reference)
#define BB 32
#define HH 128
#define WW 512
#define CC 32
#define OUT_H 64
#define OUT_W 256

// Each thread handles one output pixel's channel quads c2 and c2+4 (two
// float4s, 32 B). 4 consecutive lanes = one output pixel (128 B contiguous
// across the two loads). Blocks are swizzled so the ~32 blocks co-resident on
// one XCD cover consecutive output rows of one batch -> gather footprint
// (~16 input rows ~= 1 MiB) fits the XCD's private 4 MiB L2.
__global__ __launch_bounds__(256) void bilin_kernel(
    const float4* __restrict__ img4,
    const float* __restrict__ theta,
    float4* __restrict__ out4)
{
    // XCD swizzle: launch-order block n lands on XCD n%8 (round-robin).
    // Give XCD k the contiguous pixel chunk k, walked sequentially.
    const int chunk = gridDim.x >> 3;                       // blocks per XCD chunk
    const int bid = (blockIdx.x & 7) * chunk + (blockIdx.x >> 3);
    const int q = bid * blockDim.x + threadIdx.x;           // 0 .. 2M-1
    const int c2 = q & 3;                                   // float4 lane-slot within pixel
    const int p  = q >> 2;                                  // pixel: b*16384 + i*256 + j
    const int j  = p & (OUT_W - 1);
    const int i  = (p >> 8) & (OUT_H - 1);
    const int b  = p >> 14;

    // theta with the reference's debug hack
    float t0 = theta[b * 6 + 0];
    float t1 = theta[b * 6 + 1];
    float t2 = theta[b * 6 + 2];
    float t3 = theta[b * 6 + 3];
    float t4 = theta[b * 6 + 4];
    float t5 = theta[b * 6 + 5];
    if (b == 0) { t3 = 0.0f; t4 = 0.0f; t5 = 0.0f; }
    if (b == 1) { t0 = 0.0f; t1 = 0.0f; t2 = 0.0f; }

    // sampling grid in [-1,1]
    const float xg = -1.0f + 2.0f * (float)j / 255.0f;
    const float yg = -1.0f + 2.0f * (float)i / 63.0f;

    const float xh = t0 * xg + t1 * yg + t2;
    const float yh = t3 * xg + t4 * yg + t5;
    const float x = 0.5f * (xh + 1.0f) * (float)WW;   // uses W, not W-1 (per ref)
    const float y = 0.5f * (yh + 1.0f) * (float)HH;

    // trunc toward zero, then clip; weights use CLIPPED coords (per ref)
    int x0 = (int)x;
    int y0 = (int)y;
    int x1 = x0 + 1;
    int y1 = y0 + 1;
    x0 = min(max(x0, 0), WW - 1);
    x1 = min(max(x1, 0), WW - 1);
    y0 = min(max(y0, 0), HH - 1);
    y1 = min(max(y1, 0), HH - 1);

    const float x0f = (float)x0, x1f = (float)x1;
    const float y0f = (float)y0, y1f = (float)y1;
    const float wA = (x1f - x) * (y1f - y);
    const float wB = (x1f - x) * (y - y0f);
    const float wC = (x - x0f) * (y1f - y);
    const float wD = (x - x0f) * (y - y0f);

    // float4 indices (image is 16,777,216 float4s -> int math is safe)
    const int base = b * (HH * WW * (CC / 4));
    const int rowA = base + (y0 * WW + x0) * (CC / 4) + c2;
    const int rowB = base + (y1 * WW + x0) * (CC / 4) + c2;
    const int rowC = base + (y0 * WW + x1) * (CC / 4) + c2;
    const int rowD = base + (y1 * WW + x1) * (CC / 4) + c2;

    // 8 independent loads in flight
    const float4 A0 = img4[rowA];
    const float4 B0 = img4[rowB];
    const float4 C0 = img4[rowC];
    const float4 D0 = img4[rowD];
    const float4 A1 = img4[rowA + 4];
    const float4 B1 = img4[rowB + 4];
    const float4 C1 = img4[rowC + 4];
    const float4 D1 = img4[rowD + 4];

    float4 o0, o1;
    o0.x = A0.x * wA + B0.x * wB + C0.x * wC + D0.x * wD;
    o0.y = A0.y * wA + B0.y * wB + C0.y * wC + D0.y * wD;
    o0.z = A0.z * wA + B0.z * wB + C0.z * wC + D0.z * wD;
    o0.w = A0.w * wA + B0.w * wB + C0.w * wC + D0.w * wD;
    o1.x = A1.x * wA + B1.x * wB + C1.x * wC + D1.x * wD;
    o1.y = A1.y * wA + B1.y * wB + C1.y * wC + D1.y * wD;
    o1.z = A1.z * wA + B1.z * wB + C1.z * wC + D1.z * wD;
    o1.w = A1.w * wA + B1.w * wB + C1.w * wC + D1.w * wD;

    const int o = p * (CC / 4) + c2;
    out4[o]     = o0;
    out4[o + 4] = o1;
}

extern "C" void kernel_launch(void* const* d_in, const int* in_sizes, int n_in,
                              void* d_out, int out_size, void* d_ws, size_t ws_size,
                              hipStream_t stream) {
    const float4* img4 = (const float4*)d_in[0];
    const float* theta = (const float*)d_in[1];
    float4* out4 = (float4*)d_out;

    const int total_threads = BB * OUT_H * OUT_W * 4;  // 2,097,152 (4 threads/pixel)
    const int block = 256;
    const int grid = total_threads / block;            // 8192
    bilin_kernel<<<grid, block, 0, stream>>>(img4, theta, out4);
}

// Round 4
// 327.884 us; speedup vs baseline: 1.0316x; 1.0316x over previous
//
#include <hip/hip_runtime.h>

// Problem constants (from reference)
#define BB 32
#define HH 128
#define WW 512
#define CC 32
#define OUT_H 64
#define OUT_W 256

// Native vector type (clang ext_vector) — accepted by __builtin_nontemporal_*
typedef float vfloat4 __attribute__((ext_vector_type(4)));

// One thread per output float4 (4 channels). 8 consecutive lanes = one output
// pixel (32 channels, 128 B contiguous). Output stored non-temporally so the
// write-once 67 MB stream does not evict gather-reuse lines from L2.
__global__ __launch_bounds__(256) void bilin_kernel(
    const vfloat4* __restrict__ img4,
    const float* __restrict__ theta,
    vfloat4* __restrict__ out4)
{
    const int gid = blockIdx.x * blockDim.x + threadIdx.x;
    const int c4 = gid & 7;          // float4 slot within the 32 channels
    const int p  = gid >> 3;         // pixel index: b*16384 + i*256 + j
    const int j  = p & (OUT_W - 1);
    const int i  = (p >> 8) & (OUT_H - 1);
    const int b  = p >> 14;

    // b is wave-uniform (8 pixels/wave, batch = 16384 pixels) -> scalarize
    const int bu = __builtin_amdgcn_readfirstlane(b);
    float t0 = theta[bu * 6 + 0];
    float t1 = theta[bu * 6 + 1];
    float t2 = theta[bu * 6 + 2];
    float t3 = theta[bu * 6 + 3];
    float t4 = theta[bu * 6 + 4];
    float t5 = theta[bu * 6 + 5];
    // reference's debug hack
    if (bu == 0) { t3 = 0.0f; t4 = 0.0f; t5 = 0.0f; }
    if (bu == 1) { t0 = 0.0f; t1 = 0.0f; t2 = 0.0f; }

    // sampling grid in [-1,1]
    const float xg = -1.0f + 2.0f * (float)j / 255.0f;
    const float yg = -1.0f + 2.0f * (float)i / 63.0f;

    const float xh = t0 * xg + t1 * yg + t2;
    const float yh = t3 * xg + t4 * yg + t5;
    const float x = 0.5f * (xh + 1.0f) * (float)WW;   // uses W, not W-1 (per ref)
    const float y = 0.5f * (yh + 1.0f) * (float)HH;

    // trunc toward zero, then clip; weights use CLIPPED coords (per ref)
    int x0 = (int)x;
    int y0 = (int)y;
    int x1 = x0 + 1;
    int y1 = y0 + 1;
    x0 = min(max(x0, 0), WW - 1);
    x1 = min(max(x1, 0), WW - 1);
    y0 = min(max(y0, 0), HH - 1);
    y1 = min(max(y1, 0), HH - 1);

    const float x0f = (float)x0, x1f = (float)x1;
    const float y0f = (float)y0, y1f = (float)y1;
    const float wA = (x1f - x) * (y1f - y);
    const float wB = (x1f - x) * (y - y0f);
    const float wC = (x - x0f) * (y1f - y);
    const float wD = (x - x0f) * (y - y0f);

    // float4 indices (image is 16,777,216 float4s -> int math safe)
    const int base = bu * (HH * WW * (CC / 4));
    const vfloat4 pA = img4[base + (y0 * WW + x0) * (CC / 4) + c4];
    const vfloat4 pB = img4[base + (y1 * WW + x0) * (CC / 4) + c4];
    const vfloat4 pC = img4[base + (y0 * WW + x1) * (CC / 4) + c4];
    const vfloat4 pD = img4[base + (y1 * WW + x1) * (CC / 4) + c4];

    const vfloat4 o = pA * wA + pB * wB + pC * wC + pD * wD;

    // non-temporal: keep the write-once output stream out of L2
    __builtin_nontemporal_store(o, &out4[gid]);
}

extern "C" void kernel_launch(void* const* d_in, const int* in_sizes, int n_in,
                              void* d_out, int out_size, void* d_ws, size_t ws_size,
                              hipStream_t stream) {
    const vfloat4* img4 = (const vfloat4*)d_in[0];
    const float* theta = (const float*)d_in[1];
    vfloat4* out4 = (vfloat4*)d_out;

    const int total4 = BB * OUT_H * OUT_W * (CC / 4);  // 4,194,304
    const int block = 256;
    const int grid = total4 / block;                   // 16,384
    bilin_kernel<<<grid, block, 0, stream>>>(img4, theta, out4);
}